// Round 1
// baseline (1364.570 us; speedup 1.0000x reference)
//
#include <hip/hip_runtime.h>
#include <math.h>

#define NPIX 16384
#define EPSF 1e-8f

__device__ __forceinline__ float wred64(float s){
  s += __shfl_xor(s, 32); s += __shfl_xor(s, 16); s += __shfl_xor(s, 8);
  s += __shfl_xor(s, 4);  s += __shfl_xor(s, 2);  s += __shfl_xor(s, 1);
  return s;
}
__device__ __forceinline__ float rdlane(float v, int l){
  return __int_as_float(__builtin_amdgcn_readlane(__float_as_int(v), l));
}
__device__ __forceinline__ float dot4f(float4 a, float4 b, float acc){
  acc = fmaf(a.x,b.x,acc); acc = fmaf(a.y,b.y,acc);
  acc = fmaf(a.z,b.z,acc); acc = fmaf(a.w,b.w,acc);
  return acc;
}

// ---------------- prep: transpose conv weights to [tap][cin4][cout][4], zero stats ----------------
__global__ __launch_bounds__(256) void prep_kernel(const float* __restrict__ w_bb2, const float* __restrict__ w_k1,
                            const float* __restrict__ w_k2, const float* __restrict__ w_q1,
                            const float* __restrict__ w_q2, const float* __restrict__ w_kp,
                            const float* __restrict__ w_qp, float* __restrict__ wt, float* __restrict__ stats){
  int gid = blockIdx.x*256 + threadIdx.x;
  if (gid < 184320){
    int conv = gid / 36864; int d = gid % 36864;
    const float* src = conv==0? w_bb2 : conv==1? w_k1 : conv==2? w_k2 : conv==3? w_q1 : w_q2;
    int k = d & 3, cout = (d>>2) & 63, cin4 = (d>>8) & 15, tap = d >> 12;
    wt[conv*36864 + d] = src[(tap*64 + cin4*4 + k)*64 + cout];
  } else if (gid < 192512){
    int t = gid - 184320; int which = t >> 12; int d = t & 4095;
    const float* src = which ? w_qp : w_kp;
    int k = d & 3, cout = (d>>2) & 63, cin4 = d >> 8;
    wt[184320 + t] = src[(cin4*4 + k)*64 + cout];
  } else if (gid < 193024){
    stats[gid - 192512] = 0.f;
  }
}

// ---------------- conv1: 3x3, Cin=3 -> 64, bias + relu ----------------
__global__ __launch_bounds__(256) void conv1_kernel(const float* __restrict__ x, const float* __restrict__ w,
                                                    const float* __restrict__ bias, float* __restrict__ out){
  int gid = blockIdx.x*256 + threadIdx.x;
  int c = gid & 63; int pix = gid >> 6;
  int b = pix >> 14; int i = pix & (NPIX-1);
  int y = i >> 7, xx = i & 127;
  float acc = bias[c];
  #pragma unroll
  for (int ky=0; ky<3; ++ky){
    int ny = y + ky - 1;
    if ((unsigned)ny < 128u){
      #pragma unroll
      for (int kx=0; kx<3; ++kx){
        int nx = xx + kx - 1;
        if ((unsigned)nx < 128u){
          const float* ip = x + ((b<<14) + ny*128 + nx)*3;
          const float* wp = w + ((ky*3+kx)*3)*64 + c;
          acc = fmaf(ip[0], wp[0],   acc);
          acc = fmaf(ip[1], wp[64],  acc);
          acc = fmaf(ip[2], wp[128], acc);
        }
      }
    }
  }
  out[pix*64 + c] = fmaxf(acc, 0.f);
}

// ---------------- conv3x3 64->64 (wave = 8 px x 64 cout) ----------------
__global__ __launch_bounds__(256) void conv3_kernel(const float* __restrict__ in, const float* __restrict__ wt,
                                                    const float* __restrict__ bias, float* __restrict__ out, int relu){
  int wv = blockIdx.x*4 + (threadIdx.x >> 6);
  int c  = threadIdx.x & 63;
  int p0 = wv << 3;
  int b  = p0 >> 14; int i0 = p0 & (NPIX-1);
  int y  = i0 >> 7, x0 = i0 & 127;
  float bv = bias ? bias[c] : 0.f;
  float acc[8];
  #pragma unroll
  for (int k=0;k<8;++k) acc[k] = bv;
  bool interior = (x0 > 0) && (x0 < 120);
  for (int ky=0; ky<3; ++ky){
    int ny = y + ky - 1;
    if ((unsigned)ny >= 128u) continue;
    const float* row = in + (((b<<14) + ny*128) << 6);
    for (int kx=0; kx<3; ++kx){
      const float4* wq = (const float4*)(wt + (((ky*3+kx)) << 12));
      int cbase = x0 + kx - 1;
      for (int cb=0; cb<4; ++cb){
        int cb4 = cb*4;
        float4 w0 = wq[((cb4+0)<<6) + c];
        float4 w1 = wq[((cb4+1)<<6) + c];
        float4 w2 = wq[((cb4+2)<<6) + c];
        float4 w3 = wq[((cb4+3)<<6) + c];
        if (interior){
          #pragma unroll
          for (int k=0;k<8;++k){
            const float4* ip = (const float4*)(row + ((cbase+k)<<6));
            acc[k] = dot4f(ip[cb4+0], w0, acc[k]);
            acc[k] = dot4f(ip[cb4+1], w1, acc[k]);
            acc[k] = dot4f(ip[cb4+2], w2, acc[k]);
            acc[k] = dot4f(ip[cb4+3], w3, acc[k]);
          }
        } else {
          #pragma unroll
          for (int k=0;k<8;++k){
            int col = cbase + k;
            if ((unsigned)col < 128u){
              const float4* ip = (const float4*)(row + (col<<6));
              acc[k] = dot4f(ip[cb4+0], w0, acc[k]);
              acc[k] = dot4f(ip[cb4+1], w1, acc[k]);
              acc[k] = dot4f(ip[cb4+2], w2, acc[k]);
              acc[k] = dot4f(ip[cb4+3], w3, acc[k]);
            }
          }
        }
      }
    }
  }
  float* op = out + (p0 << 6) + c;
  #pragma unroll
  for (int k=0;k<8;++k){
    float v = acc[k];
    if (relu) v = fmaxf(v, 0.f);
    op[k*64] = v;
  }
}

// ---------------- per-channel mean/var accumulation ----------------
__global__ __launch_bounds__(256) void stats_kernel(const float* __restrict__ t, float* __restrict__ stats){
  __shared__ float s1[64], s2[64];
  int tid = threadIdx.x;
  if (tid < 64){ s1[tid] = 0.f; s2[tid] = 0.f; }
  __syncthreads();
  int gid = blockIdx.x*256 + tid;
  float sum = 0.f, ss = 0.f;
  for (int idx = gid; idx < 2097152; idx += 131072){
    float v = t[idx]; sum += v; ss += v*v;
  }
  int c = gid & 63;
  atomicAdd(&s1[c], sum);
  atomicAdd(&s2[c], ss);
  __syncthreads();
  if (tid < 64){ atomicAdd(&stats[tid], s1[tid]); atomicAdd(&stats[64+tid], s2[tid]); }
}

// ---------------- t = relu(a*t + b) (BN+ReLU in place) ----------------
__global__ __launch_bounds__(256) void bnrelu_kernel(float* __restrict__ t, const float* __restrict__ stats,
                                                     const float* __restrict__ g, const float* __restrict__ beta){
  int idx4 = blockIdx.x*256 + threadIdx.x;
  float4 v = ((float4*)t)[idx4];
  int c0 = (idx4 & 15) * 4;
  float a[4], bb[4];
  #pragma unroll
  for (int j=0;j<4;++j){
    int c = c0 + j;
    float mu  = stats[c]    * (1.f/32768.f);
    float var = stats[64+c] * (1.f/32768.f) - mu*mu;
    a[j]  = g[c] * rsqrtf(var + 1e-5f);
    bb[j] = beta[c] - mu*a[j];
  }
  v.x = fmaxf(fmaf(v.x, a[0], bb[0]), 0.f);
  v.y = fmaxf(fmaf(v.y, a[1], bb[1]), 0.f);
  v.z = fmaxf(fmaf(v.z, a[2], bb[2]), 0.f);
  v.w = fmaxf(fmaf(v.w, a[3], bb[3]), 0.f);
  ((float4*)t)[idx4] = v;
}

// ---------------- t = relu(f + a*t + b) (BN + residual + ReLU in place) ----------------
__global__ __launch_bounds__(256) void resfuse_kernel(float* __restrict__ t, const float* __restrict__ f,
                                                      const float* __restrict__ stats, const float* __restrict__ g,
                                                      const float* __restrict__ beta){
  int idx4 = blockIdx.x*256 + threadIdx.x;
  float4 v = ((float4*)t)[idx4];
  float4 fv = ((const float4*)f)[idx4];
  int c0 = (idx4 & 15) * 4;
  float a[4], bb[4];
  #pragma unroll
  for (int j=0;j<4;++j){
    int c = c0 + j;
    float mu  = stats[c]    * (1.f/32768.f);
    float var = stats[64+c] * (1.f/32768.f) - mu*mu;
    a[j]  = g[c] * rsqrtf(var + 1e-5f);
    bb[j] = beta[c] - mu*a[j];
  }
  v.x = fmaxf(fv.x + fmaf(v.x, a[0], bb[0]), 0.f);
  v.y = fmaxf(fv.y + fmaf(v.y, a[1], bb[1]), 0.f);
  v.z = fmaxf(fv.z + fmaf(v.z, a[2], bb[2]), 0.f);
  v.w = fmaxf(fv.w + fmaf(v.w, a[3], bb[3]), 0.f);
  ((float4*)t)[idx4] = v;
}

// ---------------- 1x1 projection + per-pixel L2 norm ----------------
__global__ __launch_bounds__(256) void proj_kernel(const float* __restrict__ r, const float* __restrict__ wt1,
                                                   const float* __restrict__ bias, float* __restrict__ out,
                                                   float* __restrict__ nrm){
  int wv = blockIdx.x*4 + (threadIdx.x >> 6);   // global pixel 0..32767
  int c  = threadIdx.x & 63;
  const float4* rp = (const float4*)(r + (wv << 6));
  const float4* wq = (const float4*)wt1;
  float acc0 = bias ? bias[c] : 0.f;
  float acc1 = 0.f;
  #pragma unroll
  for (int q=0; q<16; q+=2){
    acc0 = dot4f(rp[q],   wq[((q  )<<6)+c], acc0);
    acc1 = dot4f(rp[q+1], wq[((q+1)<<6)+c], acc1);
  }
  float acc = acc0 + acc1;
  out[(wv<<6) + c] = acc;
  float s = wred64(acc*acc);
  if (c == 0) nrm[wv] = sqrtf(s);
}

// ---------------- edge weights: W[b,i,o] = cos-sim(q_i, k_j) for 5x5 offsets ----------------
#define EW_PAD 68
__global__ __launch_bounds__(256) void edge_kernel(const float* __restrict__ qs, const float* __restrict__ ks,
                                                   const float* __restrict__ nq, const float* __restrict__ nk,
                                                   float* __restrict__ W){
  __shared__ float klds[100*EW_PAD];
  __shared__ float qlds[16*EW_PAD];
  int blk = blockIdx.x;              // 2048 = 2 batches * 128 rows * 8
  int b = blk >> 10; int rem = blk & 1023;
  int y = rem >> 3; int x0 = (rem & 7) << 4;
  int tid = threadIdx.x;
  for (int s = tid; s < 1600; s += 256){
    int cin4 = s & 15; int col = (s >> 4) % 20; int r = (s >> 4) / 20;
    int ry = y - 2 + r; ry = ry < 0 ? 0 : (ry > 127 ? 127 : ry);
    int cx = x0 - 2 + col; cx = cx < 0 ? 0 : (cx > 127 ? 127 : cx);
    float4 v = *(const float4*)(ks + (((b<<14) + ry*128 + cx)<<6) + cin4*4);
    *(float4*)(klds + (r*20+col)*EW_PAD + cin4*4) = v;
  }
  {
    int cin4 = tid & 15; int px = tid >> 4;
    float4 v = *(const float4*)(qs + (((b<<14) + y*128 + x0 + px)<<6) + cin4*4);
    *(float4*)(qlds + px*EW_PAD + cin4*4) = v;
  }
  __syncthreads();
  #pragma unroll
  for (int pair=0; pair<2; ++pair){
    int t2 = tid + pair*256;
    int px = t2 >> 5; int o = t2 & 31;
    if (o < 25){
      int dy = o/5 - 2, dx = o%5 - 2;
      int yy = y + dy, xx = x0 + px + dx;
      bool valid = ((unsigned)yy < 128u) && ((unsigned)xx < 128u);
      const float* kq = klds + ((dy+2)*20 + (px+dx+2))*EW_PAD;
      const float* qq = qlds + px*EW_PAD;
      float a0 = 0.f, a1 = 0.f;
      #pragma unroll
      for (int q=0; q<16; q+=2){
        a0 = dot4f(*(const float4*)(qq + q*4),     *(const float4*)(kq + q*4),     a0);
        a1 = dot4f(*(const float4*)(qq + (q+1)*4), *(const float4*)(kq + (q+1)*4), a1);
      }
      float acc = a0 + a1;
      int gp = (b<<14) + y*128 + x0 + px;
      float wv_ = 0.f;
      if (valid){
        int gj = (b<<14) + yy*128 + xx;
        float rq = 1.f / fmaxf(nq[gp], EPSF);
        float rk = 1.f / fmaxf(nk[gj], EPSF);
        wv_ = acc * rq * rk;
      }
      W[gp*25 + o] = wv_;
    }
  }
}

// ---------------- one message-passing iteration (register sliding window) ----------------
__global__ __launch_bounds__(256) void mp_iter_kernel(const float* __restrict__ src, float* __restrict__ dst,
                                                      const float* __restrict__ W){
  int lane = threadIdx.x & 63;
  int wid  = threadIdx.x >> 6;
  int blk  = blockIdx.x;               // 1024
  int xcd = blk & 7, s = blk >> 3;     // XCD-contiguous rows for L2 locality
  int row_id = xcd*32 + (s >> 2);      // 0..255 (2 batches x 128 rows)
  int q4 = s & 3;
  int b = row_id >> 7, y = row_id & 127;
  int x0 = ((q4 << 2) + wid) << 3;     // 8-pixel group start col
  int gp0 = (b << 14) + y*128 + x0;
  int lo = lane < 25 ? lane : 24;
  float wv[8];
  #pragma unroll
  for (int p=0;p<8;++p) wv[p] = W[(gp0+p)*25 + lo];
  const float* rp[5];
  #pragma unroll
  for (int r=0;r<5;++r){
    int ry = y - 2 + r; ry = ry < 0 ? 0 : (ry > 127 ? 127 : ry);
    rp[r] = src + (((b<<14) + ry*128) << 7) + lane;
  }
  float wa[5][5], wb[5][5];
  #pragma unroll
  for (int cc=0; cc<4; ++cc){
    int xc = x0 - 2 + cc; if (xc < 0) xc = 0;
    int off = xc << 7;
    #pragma unroll
    for (int r=0;r<5;++r){ wa[r][cc] = rp[r][off]; wb[r][cc] = rp[r][off + 64]; }
  }
  #pragma unroll
  for (int p=0;p<8;++p){
    int xl = x0 + p + 2; if (xl > 127) xl = 127;
    int off = xl << 7;
    #pragma unroll
    for (int r=0;r<5;++r){ wa[r][4] = rp[r][off]; wb[r][4] = rp[r][off + 64]; }
    float a0 = 0.f, a1 = 0.f;
    #pragma unroll
    for (int r=0;r<5;++r){
      #pragma unroll
      for (int cc=0;cc<5;++cc){
        float w = rdlane(wv[p], r*5+cc);
        a0 = fmaf(w, wa[r][cc], a0);
        a1 = fmaf(w, wb[r][cc], a1);
      }
    }
    float ss = wred64(a0*a0 + a1*a1);
    float sc = 1.f / fmaxf(sqrtf(ss), EPSF);
    float* dp = dst + ((gp0 + p) << 7) + lane;
    dp[0] = a0*sc; dp[64] = a1*sc;
    #pragma unroll
    for (int r=0;r<5;++r){
      #pragma unroll
      for (int cc=0;cc<4;++cc){ wa[r][cc] = wa[r][cc+1]; wb[r][cc] = wb[r][cc+1]; }
    }
  }
}

// ---------------- normalize agent pixels ----------------
__global__ void mp_agents_kernel(const float* __restrict__ hf, const int* __restrict__ agidx,
                                 float* __restrict__ agbuf){
  int lane = threadIdx.x & 63; int w = threadIdx.x >> 6;  // 16 waves
  int ab = w >> 3, m = w & 7;
  int ai = agidx[m];
  const float* hp = hf + (((ab<<14) + ai) << 7) + lane;
  float v0 = hp[0], v1 = hp[64];
  float ss = wred64(v0*v0 + v1*v1);
  float sc = 1.f / fmaxf(sqrtf(ss), EPSF);
  float* ap = agbuf + (((ab<<3) + m) << 7) + lane;
  ap[0] = v0*sc; ap[64] = v1*sc;
}

// ---------------- final: pix-norm, sim vs agents, softmax, transposed write ----------------
__global__ __launch_bounds__(256) void mp_final_kernel(const float* __restrict__ hf, const float* __restrict__ agbuf,
                                                       float* __restrict__ out){
  int lane = threadIdx.x & 63;
  int wid  = threadIdx.x >> 6;
  int blk  = blockIdx.x;
  int xcd = blk & 7, s = blk >> 3;
  int row_id = xcd*32 + (s >> 2);
  int q4 = s & 3;
  int b = row_id >> 7, y = row_id & 127;
  int x0 = ((q4 << 2) + wid) << 3;
  int gp0 = (b << 14) + y*128 + x0;
  #pragma unroll 1
  for (int p=0;p<8;++p){
    int gp = gp0 + p;
    const float* hp = hf + (gp << 7) + lane;
    float v0 = hp[0], v1 = hp[64];
    float ss = wred64(v0*v0 + v1*v1);
    float sc = 1.f / fmaxf(sqrtf(ss), EPSF);
    float p0 = v0*sc, p1 = v1*sc;
    float sim[8];
    #pragma unroll
    for (int m=0;m<8;++m){
      const float* ap = agbuf + (((b<<3) + m) << 7) + lane;
      sim[m] = wred64(p0*ap[0] + p1*ap[64]);
    }
    float mx = sim[0];
    #pragma unroll
    for (int m=1;m<8;++m) mx = fmaxf(mx, sim[m]);
    float e[8]; float sum = 0.f;
    #pragma unroll
    for (int m=0;m<8;++m){ e[m] = __expf((sim[m]-mx)*10.f); sum += e[m]; }
    float rs = 1.f / sum;
    if (lane < 8){
      float val = e[0];
      #pragma unroll
      for (int m=1;m<8;++m) val = (lane==m) ? e[m] : val;
      out[(((b<<3)+lane)<<14) + y*128 + x0 + p] = val * rs;
    }
  }
}

extern "C" void kernel_launch(void* const* d_in, const int* in_sizes, int n_in,
                              void* d_out, int out_size, void* d_ws, size_t ws_size,
                              hipStream_t stream) {
  (void)in_sizes; (void)n_in; (void)out_size; (void)ws_size;
  const float* x     = (const float*)d_in[0];
  const float* w_bb1 = (const float*)d_in[1];
  const float* b_bb1 = (const float*)d_in[2];
  const float* w_bb2 = (const float*)d_in[3];
  const float* b_bb2 = (const float*)d_in[4];
  const float* w_k1  = (const float*)d_in[5];
  const float* g_k1  = (const float*)d_in[6];
  const float* t_k1  = (const float*)d_in[7];
  const float* w_k2  = (const float*)d_in[8];
  const float* g_k2  = (const float*)d_in[9];
  const float* t_k2  = (const float*)d_in[10];
  const float* w_kp  = (const float*)d_in[11];
  const float* b_kp  = (const float*)d_in[12];
  const float* w_q1  = (const float*)d_in[13];
  const float* g_q1  = (const float*)d_in[14];
  const float* t_q1  = (const float*)d_in[15];
  const float* w_q2  = (const float*)d_in[16];
  const float* g_q2  = (const float*)d_in[17];
  const float* t_q2  = (const float*)d_in[18];
  const float* w_qp  = (const float*)d_in[19];
  const float* h0    = (const float*)d_in[20];
  const int*   agidx = (const int*)d_in[23];
  float* out = (float*)d_out;
  float* ws  = (float*)d_ws;

  // workspace layout (floats); hA/hB alias conv buffers (dead by MP time)
  float* F1 = ws + 0;
  float* F  = ws + 2097152;
  float* T1 = ws + 4194304;
  float* T2 = ws + 6291456;
  float* KS = ws + 8388608;
  float* QS = ws + 10485760;
  float* WW = ws + 12582912;   // 819200
  float* NK = ws + 13402112;   // 32768
  float* NQ = ws + 13434880;   // 32768
  float* ST = ws + 13467648;   // 512
  float* AG = ws + 13468160;   // 2048
  float* WT = ws + 13470208;   // 192512
  float* HA = ws + 0;          // 4194304 (aliases F1,F)
  float* HB = ws + 4194304;    // 4194304 (aliases T1,T2)

  prep_kernel<<<755, 256, 0, stream>>>(w_bb2, w_k1, w_k2, w_q1, w_q2, w_kp, w_qp, WT, ST);
  conv1_kernel<<<8192, 256, 0, stream>>>(x, w_bb1, b_bb1, F1);
  conv3_kernel<<<1024, 256, 0, stream>>>(F1, WT + 0, b_bb2, F, 1);
  // K branch
  conv3_kernel<<<1024, 256, 0, stream>>>(F, WT + 36864, nullptr, T1, 0);
  stats_kernel<<<512, 256, 0, stream>>>(T1, ST + 0);
  bnrelu_kernel<<<2048, 256, 0, stream>>>(T1, ST + 0, g_k1, t_k1);
  conv3_kernel<<<1024, 256, 0, stream>>>(T1, WT + 73728, nullptr, T2, 0);
  stats_kernel<<<512, 256, 0, stream>>>(T2, ST + 128);
  resfuse_kernel<<<2048, 256, 0, stream>>>(T2, F, ST + 128, g_k2, t_k2);
  proj_kernel<<<8192, 256, 0, stream>>>(T2, WT + 184320, b_kp, KS, NK);
  // Q branch
  conv3_kernel<<<1024, 256, 0, stream>>>(F, WT + 110592, nullptr, T1, 0);
  stats_kernel<<<512, 256, 0, stream>>>(T1, ST + 256);
  bnrelu_kernel<<<2048, 256, 0, stream>>>(T1, ST + 256, g_q1, t_q1);
  conv3_kernel<<<1024, 256, 0, stream>>>(T1, WT + 147456, nullptr, T2, 0);
  stats_kernel<<<512, 256, 0, stream>>>(T2, ST + 384);
  resfuse_kernel<<<2048, 256, 0, stream>>>(T2, F, ST + 384, g_q2, t_q2);
  proj_kernel<<<8192, 256, 0, stream>>>(T2, WT + 188416, nullptr, QS, NQ);
  // edge weights
  edge_kernel<<<2048, 256, 0, stream>>>(QS, KS, NQ, NK, WW);
  // 32 message-passing iterations (ping-pong)
  const float* sbuf = h0;
  for (int it = 0; it < 32; ++it){
    float* dbuf = (it & 1) ? HB : HA;
    mp_iter_kernel<<<1024, 256, 0, stream>>>(sbuf, dbuf, WW);
    sbuf = dbuf;
  }
  mp_agents_kernel<<<1, 1024, 0, stream>>>(HB, agidx, AG);
  mp_final_kernel<<<1024, 256, 0, stream>>>(HB, AG, out);
}

// Round 2
// 1023.333 us; speedup vs baseline: 1.3335x; 1.3335x over previous
//
#include <hip/hip_runtime.h>
#include <math.h>

#define NPIX 16384
#define EPSF 1e-8f

__device__ __forceinline__ float wred64(float s){
  s += __shfl_xor(s, 32); s += __shfl_xor(s, 16); s += __shfl_xor(s, 8);
  s += __shfl_xor(s, 4);  s += __shfl_xor(s, 2);  s += __shfl_xor(s, 1);
  return s;
}
__device__ __forceinline__ float rdlane(float v, int l){
  return __int_as_float(__builtin_amdgcn_readlane(__float_as_int(v), l));
}
__device__ __forceinline__ float dot4f(float4 a, float4 b, float acc){
  acc = fmaf(a.x,b.x,acc); acc = fmaf(a.y,b.y,acc);
  acc = fmaf(a.z,b.z,acc); acc = fmaf(a.w,b.w,acc);
  return acc;
}

// ---------------- prep: transpose conv weights to [tap][cin4][cout][4], zero stats ----------------
__global__ __launch_bounds__(256) void prep_kernel(const float* __restrict__ w_bb2, const float* __restrict__ w_k1,
                            const float* __restrict__ w_k2, const float* __restrict__ w_q1,
                            const float* __restrict__ w_q2, const float* __restrict__ w_kp,
                            const float* __restrict__ w_qp, float* __restrict__ wt, float* __restrict__ stats){
  int gid = blockIdx.x*256 + threadIdx.x;
  if (gid < 184320){
    int conv = gid / 36864; int d = gid % 36864;
    const float* src = conv==0? w_bb2 : conv==1? w_k1 : conv==2? w_k2 : conv==3? w_q1 : w_q2;
    int k = d & 3, cout = (d>>2) & 63, cin4 = (d>>8) & 15, tap = d >> 12;
    wt[conv*36864 + d] = src[(tap*64 + cin4*4 + k)*64 + cout];
  } else if (gid < 192512){
    int t = gid - 184320; int which = t >> 12; int d = t & 4095;
    const float* src = which ? w_qp : w_kp;
    int k = d & 3, cout = (d>>2) & 63, cin4 = d >> 8;
    wt[184320 + t] = src[(cin4*4 + k)*64 + cout];
  } else if (gid < 193024){
    stats[gid - 192512] = 0.f;
  }
}

// ---------------- conv1: 3x3, Cin=3 -> 64 (wave = 8 px x 64 cout, scalar input loads) ----------------
__global__ __launch_bounds__(256) void conv1_kernel(const float* __restrict__ x, const float* __restrict__ w,
                                                    const float* __restrict__ bias, float* __restrict__ out){
  int wv = blockIdx.x*4 + (threadIdx.x >> 6);
  int c  = threadIdx.x & 63;
  int p0 = wv << 3;
  int ub = __builtin_amdgcn_readfirstlane(p0);
  int b  = ub >> 14; int i0 = ub & (NPIX-1);
  int y  = i0 >> 7, x0 = i0 & 127;
  // 27 weights per lane
  float wv_[9][3];
  #pragma unroll
  for (int t=0;t<9;++t)
    #pragma unroll
    for (int ci=0;ci<3;++ci) wv_[t][ci] = w[(t*3+ci)*64 + c];
  float bv = bias[c];
  float acc[8];
  #pragma unroll
  for (int p=0;p<8;++p) acc[p] = bv;
  for (int ky=0; ky<3; ++ky){
    int ny = y + ky - 1;
    if ((unsigned)ny >= 128u) continue;
    const float* rowp = x + ((b<<14) + ny*128)*3;
    for (int kx=0; kx<3; ++kx){
      int t = ky*3 + kx;
      #pragma unroll
      for (int p=0;p<8;++p){
        int col = x0 + p + kx - 1;
        if ((unsigned)col < 128u){
          const float* ip = rowp + col*3;
          acc[p] = fmaf(ip[0], wv_[t][0], acc[p]);
          acc[p] = fmaf(ip[1], wv_[t][1], acc[p]);
          acc[p] = fmaf(ip[2], wv_[t][2], acc[p]);
        }
      }
    }
  }
  float* op = out + (p0 << 6) + c;
  #pragma unroll
  for (int p=0;p<8;++p) op[p*64] = fmaxf(acc[p], 0.f);
}

// ---------------- conv3x3 64->64 (wave = 16 px x 64 cout; uniform/scalar input loads) ----------------
__global__ __launch_bounds__(256) void conv3_kernel(const float* __restrict__ in, const float* __restrict__ wt,
                                                    const float* __restrict__ bias, float* __restrict__ out, int relu){
  int wv = blockIdx.x*4 + (threadIdx.x >> 6);
  int c  = threadIdx.x & 63;
  int p0 = wv << 4;                       // 16 pixels per wave
  int ub = __builtin_amdgcn_readfirstlane(p0);
  int b  = ub >> 14; int i0 = ub & (NPIX-1);
  int y  = i0 >> 7, x0 = i0 & 127;
  float bv = bias ? bias[c] : 0.f;
  float acc[16];
  #pragma unroll
  for (int p=0;p<16;++p) acc[p] = bv;
  for (int ky=0; ky<3; ++ky){
    int ny = y + ky - 1;
    if ((unsigned)ny >= 128u) continue;
    const float* rowp = in + (((b<<14) + ny*128) << 6);  // uniform base
    for (int kx=0; kx<3; ++kx){
      const float4* wq = (const float4*)wt + (ky*3+kx)*1024 + c;
      #pragma unroll
      for (int h=0; h<2; ++h){            // cin halves: cin4 = h*8 + q
        float4 w[8];
        #pragma unroll
        for (int q=0;q<8;++q) w[q] = wq[(h*8+q)*64];
        #pragma unroll
        for (int p=0;p<16;++p){
          int col = x0 + p + kx - 1;
          if ((unsigned)col < 128u){
            const float* ip = rowp + (col<<6) + h*32;    // uniform address
            #pragma unroll
            for (int q=0;q<8;++q){
              float4 iv = *(const float4*)(ip + (q<<2));  // wave-uniform -> s_load
              acc[p] = dot4f(iv, w[q], acc[p]);
            }
          }
        }
      }
    }
  }
  float* op = out + (p0 << 6) + c;
  #pragma unroll
  for (int p=0;p<16;++p){
    float v = acc[p];
    if (relu) v = fmaxf(v, 0.f);
    op[p*64] = v;
  }
}

// ---------------- per-channel mean/var accumulation ----------------
__global__ __launch_bounds__(256) void stats_kernel(const float* __restrict__ t, float* __restrict__ stats){
  __shared__ float s1[64], s2[64];
  int tid = threadIdx.x;
  if (tid < 64){ s1[tid] = 0.f; s2[tid] = 0.f; }
  __syncthreads();
  int gid = blockIdx.x*256 + tid;
  float sum = 0.f, ss = 0.f;
  for (int idx = gid; idx < 2097152; idx += 131072){
    float v = t[idx]; sum += v; ss += v*v;
  }
  int c = gid & 63;
  atomicAdd(&s1[c], sum);
  atomicAdd(&s2[c], ss);
  __syncthreads();
  if (tid < 64){ atomicAdd(&stats[tid], s1[tid]); atomicAdd(&stats[64+tid], s2[tid]); }
}

// ---------------- t = relu(a*t + b) (BN+ReLU in place) ----------------
__global__ __launch_bounds__(256) void bnrelu_kernel(float* __restrict__ t, const float* __restrict__ stats,
                                                     const float* __restrict__ g, const float* __restrict__ beta){
  int idx4 = blockIdx.x*256 + threadIdx.x;
  float4 v = ((float4*)t)[idx4];
  int c0 = (idx4 & 15) * 4;
  float a[4], bb[4];
  #pragma unroll
  for (int j=0;j<4;++j){
    int c = c0 + j;
    float mu  = stats[c]    * (1.f/32768.f);
    float var = stats[64+c] * (1.f/32768.f) - mu*mu;
    a[j]  = g[c] * rsqrtf(var + 1e-5f);
    bb[j] = beta[c] - mu*a[j];
  }
  v.x = fmaxf(fmaf(v.x, a[0], bb[0]), 0.f);
  v.y = fmaxf(fmaf(v.y, a[1], bb[1]), 0.f);
  v.z = fmaxf(fmaf(v.z, a[2], bb[2]), 0.f);
  v.w = fmaxf(fmaf(v.w, a[3], bb[3]), 0.f);
  ((float4*)t)[idx4] = v;
}

// ---------------- t = relu(f + a*t + b) (BN + residual + ReLU in place) ----------------
__global__ __launch_bounds__(256) void resfuse_kernel(float* __restrict__ t, const float* __restrict__ f,
                                                      const float* __restrict__ stats, const float* __restrict__ g,
                                                      const float* __restrict__ beta){
  int idx4 = blockIdx.x*256 + threadIdx.x;
  float4 v = ((float4*)t)[idx4];
  float4 fv = ((const float4*)f)[idx4];
  int c0 = (idx4 & 15) * 4;
  float a[4], bb[4];
  #pragma unroll
  for (int j=0;j<4;++j){
    int c = c0 + j;
    float mu  = stats[c]    * (1.f/32768.f);
    float var = stats[64+c] * (1.f/32768.f) - mu*mu;
    a[j]  = g[c] * rsqrtf(var + 1e-5f);
    bb[j] = beta[c] - mu*a[j];
  }
  v.x = fmaxf(fv.x + fmaf(v.x, a[0], bb[0]), 0.f);
  v.y = fmaxf(fv.y + fmaf(v.y, a[1], bb[1]), 0.f);
  v.z = fmaxf(fv.z + fmaf(v.z, a[2], bb[2]), 0.f);
  v.w = fmaxf(fv.w + fmaf(v.w, a[3], bb[3]), 0.f);
  ((float4*)t)[idx4] = v;
}

// ---------------- 1x1 projection + per-pixel L2 norm (wave = 8 px x 64 cout) ----------------
__global__ __launch_bounds__(256) void proj_kernel(const float* __restrict__ r, const float* __restrict__ wt1,
                                                   const float* __restrict__ bias, float* __restrict__ out,
                                                   float* __restrict__ nrm){
  int wv = blockIdx.x*4 + (threadIdx.x >> 6);
  int c  = threadIdx.x & 63;
  int p0 = wv << 3;
  int ub = __builtin_amdgcn_readfirstlane(p0);
  const float4* wq = (const float4*)wt1 + c;
  float4 w[16];
  #pragma unroll
  for (int q=0;q<16;++q) w[q] = wq[q*64];
  float bv = bias ? bias[c] : 0.f;
  #pragma unroll
  for (int p=0;p<8;++p){
    const float* ip = r + ((ub + p) << 6);   // uniform address
    float a0 = bv, a1 = 0.f;
    #pragma unroll
    for (int q=0;q<16;q+=2){
      float4 i0 = *(const float4*)(ip + (q<<2));
      float4 i1 = *(const float4*)(ip + ((q+1)<<2));
      a0 = dot4f(i0, w[q],   a0);
      a1 = dot4f(i1, w[q+1], a1);
    }
    float acc = a0 + a1;
    out[((p0+p)<<6) + c] = acc;
    float s = wred64(acc*acc);
    if (c == 0) nrm[p0+p] = sqrtf(s);
  }
}

// ---------------- edge weights: W[b,i,o] = cos-sim(q_i, k_j) for 5x5 offsets ----------------
#define EW_PAD 68
__global__ __launch_bounds__(256) void edge_kernel(const float* __restrict__ qs, const float* __restrict__ ks,
                                                   const float* __restrict__ nq, const float* __restrict__ nk,
                                                   float* __restrict__ W){
  __shared__ float klds[100*EW_PAD];
  __shared__ float qlds[16*EW_PAD];
  int blk = blockIdx.x;              // 2048 = 2 batches * 128 rows * 8
  int b = blk >> 10; int rem = blk & 1023;
  int y = rem >> 3; int x0 = (rem & 7) << 4;
  int tid = threadIdx.x;
  for (int s = tid; s < 1600; s += 256){
    int cin4 = s & 15; int col = (s >> 4) % 20; int r = (s >> 4) / 20;
    int ry = y - 2 + r; ry = ry < 0 ? 0 : (ry > 127 ? 127 : ry);
    int cx = x0 - 2 + col; cx = cx < 0 ? 0 : (cx > 127 ? 127 : cx);
    float4 v = *(const float4*)(ks + (((b<<14) + ry*128 + cx)<<6) + cin4*4);
    *(float4*)(klds + (r*20+col)*EW_PAD + cin4*4) = v;
  }
  {
    int cin4 = tid & 15; int px = tid >> 4;
    float4 v = *(const float4*)(qs + (((b<<14) + y*128 + x0 + px)<<6) + cin4*4);
    *(float4*)(qlds + px*EW_PAD + cin4*4) = v;
  }
  __syncthreads();
  #pragma unroll
  for (int pair=0; pair<2; ++pair){
    int t2 = tid + pair*256;
    int px = t2 >> 5; int o = t2 & 31;
    if (o < 25){
      int dy = o/5 - 2, dx = o%5 - 2;
      int yy = y + dy, xx = x0 + px + dx;
      bool valid = ((unsigned)yy < 128u) && ((unsigned)xx < 128u);
      const float* kq = klds + ((dy+2)*20 + (px+dx+2))*EW_PAD;
      const float* qq = qlds + px*EW_PAD;
      float a0 = 0.f, a1 = 0.f;
      #pragma unroll
      for (int q=0; q<16; q+=2){
        a0 = dot4f(*(const float4*)(qq + q*4),     *(const float4*)(kq + q*4),     a0);
        a1 = dot4f(*(const float4*)(qq + (q+1)*4), *(const float4*)(kq + (q+1)*4), a1);
      }
      float acc = a0 + a1;
      int gp = (b<<14) + y*128 + x0 + px;
      float wv_ = 0.f;
      if (valid){
        int gj = (b<<14) + yy*128 + xx;
        float rq = 1.f / fmaxf(nq[gp], EPSF);
        float rk = 1.f / fmaxf(nk[gj], EPSF);
        wv_ = acc * rq * rk;
      }
      W[gp*25 + o] = wv_;
    }
  }
}

// ---------------- one message-passing iteration (register sliding window) ----------------
__global__ __launch_bounds__(256) void mp_iter_kernel(const float* __restrict__ src, float* __restrict__ dst,
                                                      const float* __restrict__ W){
  int lane = threadIdx.x & 63;
  int wid  = threadIdx.x >> 6;
  int blk  = blockIdx.x;               // 1024
  int xcd = blk & 7, s = blk >> 3;     // XCD-contiguous rows for L2 locality
  int row_id = xcd*32 + (s >> 2);      // 0..255 (2 batches x 128 rows)
  int q4 = s & 3;
  int b = row_id >> 7, y = row_id & 127;
  int x0 = ((q4 << 2) + wid) << 3;     // 8-pixel group start col
  int gp0 = (b << 14) + y*128 + x0;
  int lo = lane < 25 ? lane : 24;
  float wv[8];
  #pragma unroll
  for (int p=0;p<8;++p) wv[p] = W[(gp0+p)*25 + lo];
  const float* rp[5];
  #pragma unroll
  for (int r=0;r<5;++r){
    int ry = y - 2 + r; ry = ry < 0 ? 0 : (ry > 127 ? 127 : ry);
    rp[r] = src + (((b<<14) + ry*128) << 7) + lane;
  }
  float wa[5][5], wb[5][5];
  #pragma unroll
  for (int cc=0; cc<4; ++cc){
    int xc = x0 - 2 + cc; if (xc < 0) xc = 0;
    int off = xc << 7;
    #pragma unroll
    for (int r=0;r<5;++r){ wa[r][cc] = rp[r][off]; wb[r][cc] = rp[r][off + 64]; }
  }
  #pragma unroll
  for (int p=0;p<8;++p){
    int xl = x0 + p + 2; if (xl > 127) xl = 127;
    int off = xl << 7;
    #pragma unroll
    for (int r=0;r<5;++r){ wa[r][4] = rp[r][off]; wb[r][4] = rp[r][off + 64]; }
    float a0 = 0.f, a1 = 0.f;
    #pragma unroll
    for (int r=0;r<5;++r){
      #pragma unroll
      for (int cc=0;cc<5;++cc){
        float w = rdlane(wv[p], r*5+cc);
        a0 = fmaf(w, wa[r][cc], a0);
        a1 = fmaf(w, wb[r][cc], a1);
      }
    }
    float ss = wred64(a0*a0 + a1*a1);
    float sc = 1.f / fmaxf(sqrtf(ss), EPSF);
    float* dp = dst + ((gp0 + p) << 7) + lane;
    dp[0] = a0*sc; dp[64] = a1*sc;
    #pragma unroll
    for (int r=0;r<5;++r){
      #pragma unroll
      for (int cc=0;cc<4;++cc){ wa[r][cc] = wa[r][cc+1]; wb[r][cc] = wb[r][cc+1]; }
    }
  }
}

// ---------------- normalize agent pixels ----------------
__global__ void mp_agents_kernel(const float* __restrict__ hf, const int* __restrict__ agidx,
                                 float* __restrict__ agbuf){
  int lane = threadIdx.x & 63; int w = threadIdx.x >> 6;  // 16 waves
  int ab = w >> 3, m = w & 7;
  int ai = agidx[m];
  const float* hp = hf + (((ab<<14) + ai) << 7) + lane;
  float v0 = hp[0], v1 = hp[64];
  float ss = wred64(v0*v0 + v1*v1);
  float sc = 1.f / fmaxf(sqrtf(ss), EPSF);
  float* ap = agbuf + (((ab<<3) + m) << 7) + lane;
  ap[0] = v0*sc; ap[64] = v1*sc;
}

// ---------------- final: pix-norm, sim vs agents, softmax, transposed write ----------------
__global__ __launch_bounds__(256) void mp_final_kernel(const float* __restrict__ hf, const float* __restrict__ agbuf,
                                                       float* __restrict__ out){
  int lane = threadIdx.x & 63;
  int wid  = threadIdx.x >> 6;
  int blk  = blockIdx.x;
  int xcd = blk & 7, s = blk >> 3;
  int row_id = xcd*32 + (s >> 2);
  int q4 = s & 3;
  int b = row_id >> 7, y = row_id & 127;
  int x0 = ((q4 << 2) + wid) << 3;
  int gp0 = (b << 14) + y*128 + x0;
  #pragma unroll 1
  for (int p=0;p<8;++p){
    int gp = gp0 + p;
    const float* hp = hf + (gp << 7) + lane;
    float v0 = hp[0], v1 = hp[64];
    float ss = wred64(v0*v0 + v1*v1);
    float sc = 1.f / fmaxf(sqrtf(ss), EPSF);
    float p0 = v0*sc, p1 = v1*sc;
    float sim[8];
    #pragma unroll
    for (int m=0;m<8;++m){
      const float* ap = agbuf + (((b<<3) + m) << 7) + lane;
      sim[m] = wred64(p0*ap[0] + p1*ap[64]);
    }
    float mx = sim[0];
    #pragma unroll
    for (int m=1;m<8;++m) mx = fmaxf(mx, sim[m]);
    float e[8]; float sum = 0.f;
    #pragma unroll
    for (int m=0;m<8;++m){ e[m] = __expf((sim[m]-mx)*10.f); sum += e[m]; }
    float rs = 1.f / sum;
    if (lane < 8){
      float val = e[0];
      #pragma unroll
      for (int m=1;m<8;++m) val = (lane==m) ? e[m] : val;
      out[(((b<<3)+lane)<<14) + y*128 + x0 + p] = val * rs;
    }
  }
}

extern "C" void kernel_launch(void* const* d_in, const int* in_sizes, int n_in,
                              void* d_out, int out_size, void* d_ws, size_t ws_size,
                              hipStream_t stream) {
  (void)in_sizes; (void)n_in; (void)out_size; (void)ws_size;
  const float* x     = (const float*)d_in[0];
  const float* w_bb1 = (const float*)d_in[1];
  const float* b_bb1 = (const float*)d_in[2];
  const float* w_bb2 = (const float*)d_in[3];
  const float* b_bb2 = (const float*)d_in[4];
  const float* w_k1  = (const float*)d_in[5];
  const float* g_k1  = (const float*)d_in[6];
  const float* t_k1  = (const float*)d_in[7];
  const float* w_k2  = (const float*)d_in[8];
  const float* g_k2  = (const float*)d_in[9];
  const float* t_k2  = (const float*)d_in[10];
  const float* w_kp  = (const float*)d_in[11];
  const float* b_kp  = (const float*)d_in[12];
  const float* w_q1  = (const float*)d_in[13];
  const float* g_q1  = (const float*)d_in[14];
  const float* t_q1  = (const float*)d_in[15];
  const float* w_q2  = (const float*)d_in[16];
  const float* g_q2  = (const float*)d_in[17];
  const float* t_q2  = (const float*)d_in[18];
  const float* w_qp  = (const float*)d_in[19];
  const float* h0    = (const float*)d_in[20];
  const int*   agidx = (const int*)d_in[23];
  float* out = (float*)d_out;
  float* ws  = (float*)d_ws;

  // workspace layout (floats); hA/hB alias conv buffers (dead by MP time)
  float* F1 = ws + 0;
  float* F  = ws + 2097152;
  float* T1 = ws + 4194304;
  float* T2 = ws + 6291456;
  float* KS = ws + 8388608;
  float* QS = ws + 10485760;
  float* WW = ws + 12582912;   // 819200
  float* NK = ws + 13402112;   // 32768
  float* NQ = ws + 13434880;   // 32768
  float* ST = ws + 13467648;   // 512
  float* AG = ws + 13468160;   // 2048
  float* WT = ws + 13470208;   // 192512
  float* HA = ws + 0;          // 4194304 (aliases F1,F)
  float* HB = ws + 4194304;    // 4194304 (aliases T1,T2)

  prep_kernel<<<755, 256, 0, stream>>>(w_bb2, w_k1, w_k2, w_q1, w_q2, w_kp, w_qp, WT, ST);
  conv1_kernel<<<1024, 256, 0, stream>>>(x, w_bb1, b_bb1, F1);
  conv3_kernel<<<512, 256, 0, stream>>>(F1, WT + 0, b_bb2, F, 1);
  // K branch
  conv3_kernel<<<512, 256, 0, stream>>>(F, WT + 36864, nullptr, T1, 0);
  stats_kernel<<<512, 256, 0, stream>>>(T1, ST + 0);
  bnrelu_kernel<<<2048, 256, 0, stream>>>(T1, ST + 0, g_k1, t_k1);
  conv3_kernel<<<512, 256, 0, stream>>>(T1, WT + 73728, nullptr, T2, 0);
  stats_kernel<<<512, 256, 0, stream>>>(T2, ST + 128);
  resfuse_kernel<<<2048, 256, 0, stream>>>(T2, F, ST + 128, g_k2, t_k2);
  proj_kernel<<<1024, 256, 0, stream>>>(T2, WT + 184320, b_kp, KS, NK);
  // Q branch
  conv3_kernel<<<512, 256, 0, stream>>>(F, WT + 110592, nullptr, T1, 0);
  stats_kernel<<<512, 256, 0, stream>>>(T1, ST + 256);
  bnrelu_kernel<<<2048, 256, 0, stream>>>(T1, ST + 256, g_q1, t_q1);
  conv3_kernel<<<512, 256, 0, stream>>>(T1, WT + 147456, nullptr, T2, 0);
  stats_kernel<<<512, 256, 0, stream>>>(T2, ST + 384);
  resfuse_kernel<<<2048, 256, 0, stream>>>(T2, F, ST + 384, g_q2, t_q2);
  proj_kernel<<<1024, 256, 0, stream>>>(T2, WT + 188416, nullptr, QS, NQ);
  // edge weights
  edge_kernel<<<2048, 256, 0, stream>>>(QS, KS, NQ, NK, WW);
  // 32 message-passing iterations (ping-pong)
  const float* sbuf = h0;
  for (int it = 0; it < 32; ++it){
    float* dbuf = (it & 1) ? HB : HA;
    mp_iter_kernel<<<1024, 256, 0, stream>>>(sbuf, dbuf, WW);
    sbuf = dbuf;
  }
  mp_agents_kernel<<<1, 1024, 0, stream>>>(HB, agidx, AG);
  mp_final_kernel<<<1024, 256, 0, stream>>>(HB, AG, out);
}